// Round 1
// baseline (129.519 us; speedup 1.0000x reference)
//
#include <hip/hip_runtime.h>

// QuantumKernelMethod, fully fused: out[i][j] = |tr(Q_i M_j)|
// Q_i = phi phi^T (phi = V(a_i)|0>), M_j = I - 2P, P = sum_{p:wire0=1} w_p w_p^dag.
// Hermitian pack (K=256): S[k][l] = diag | sqrt2*Re (k<l) | sqrt2*Im mirror (k>l);
// dot(S_Q, S_M) = tr(QM) exactly.
//
// Single kernel, zero workspace: each 64x64 output tile block recomputes its
// 64 Q-rows + 64 M-cols in LDS (16x redundant M work << idle capacity), then
// does the K=256 bf16 MFMA GEMM from LDS. 256 blocks (1/CU), 512 threads.
//
// LDS (76.5 KB), two time-aliased phases:
//  A: Wr/Wi [y][p][17] f32 (17-pad => sim-writes, l-reads AND runtime-k reads
//     are all <=2-way bank conflicts) + Phi [i][17] f32
//  B: Qs (32KB) + Ms (32KB) bf16, 512B/row, 16B-unit XOR swizzle
//     byte = row*512 + (col ^ ((row&15)<<4))  -> conflict-free ds_read_b128.

#define NA 1024
#define NB 1024
#define RT2 1.41421356237f

typedef __attribute__((ext_vector_type(8))) short bf16x8;
typedef __attribute__((ext_vector_type(4))) float f32x4;

__device__ __forceinline__ unsigned short f2bf(float x) {
    union { float f; unsigned u; } v; v.f = x;
    unsigned r = v.u + 0x7fffu + ((v.u >> 16) & 1u);  // RNE
    return (unsigned short)(r >> 16);
}

__device__ __forceinline__ uint4 pack8(const float* f) {
    uint4 u;
    u.x = (unsigned)f2bf(f[0]) | ((unsigned)f2bf(f[1]) << 16);
    u.y = (unsigned)f2bf(f[2]) | ((unsigned)f2bf(f[3]) << 16);
    u.z = (unsigned)f2bf(f[4]) | ((unsigned)f2bf(f[5]) << 16);
    u.w = (unsigned)f2bf(f[6]) | ((unsigned)f2bf(f[7]) << 16);
    return u;
}

// State: 16 complex amps, flat index = b0*8 + b1*4 + b2*2 + b3 (wire w -> bit 3-w)
__device__ __forceinline__ void ry_gate(float* sr, float* si, int w, float t) {
    float s, c; __sincosf(0.5f * t, &s, &c);
    int st = 8 >> w;
    #pragma unroll
    for (int b = 0; b < 16; ++b) {
        if (b & st) continue;
        int j = b | st;
        float r0 = sr[b], i0 = si[b], r1 = sr[j], i1 = si[j];
        sr[b] = c * r0 - s * r1;  si[b] = c * i0 - s * i1;
        sr[j] = s * r0 + c * r1;  si[j] = s * i0 + c * i1;
    }
}

__device__ __forceinline__ void rx_gate(float* sr, float* si, int w, float t) {
    float s, c; __sincosf(0.5f * t, &s, &c);
    int st = 8 >> w;
    #pragma unroll
    for (int b = 0; b < 16; ++b) {
        if (b & st) continue;
        int j = b | st;
        float r0 = sr[b], i0 = si[b], r1 = sr[j], i1 = si[j];
        sr[b] = c * r0 + s * i1;  si[b] = c * i0 - s * r1;
        sr[j] = c * r1 + s * i0;  si[j] = c * i1 - s * r0;
    }
}

__device__ __forceinline__ void rz_gate(float* sr, float* si, int w, float t) {
    float s, c; __sincosf(0.5f * t, &s, &c);
    int st = 8 >> w;
    #pragma unroll
    for (int b = 0; b < 16; ++b) {
        if (b & st) continue;
        int j = b | st;
        float r0 = sr[b], i0 = si[b], r1 = sr[j], i1 = si[j];
        sr[b] = c * r0 + s * i0;  si[b] = c * i0 - s * r0;
        sr[j] = c * r1 - s * i1;  si[j] = c * i1 + s * r1;
    }
}

__device__ __forceinline__ void cnot_gate(float* sr, float* si, int cw, int tw) {
    int cs = 8 >> cw, ts = 8 >> tw;
    #pragma unroll
    for (int b = 0; b < 16; ++b) {
        if ((b & cs) && !(b & ts)) {
            int j = b | ts;
            float tr = sr[b]; sr[b] = sr[j]; sr[j] = tr;
            float ti = si[b]; si[b] = si[j]; si[j] = ti;
        }
    }
}

__device__ __forceinline__ void ansatz(float* sr, float* si, const float* vec, const float* P) {
    #pragma unroll
    for (int q = 0; q < 4; ++q) ry_gate(sr, si, q, vec[q]);
    #pragma unroll
    for (int l = 0; l < 2; ++l) {
        #pragma unroll
        for (int q = 0; q < 4; ++q) {
            rx_gate(sr, si, q, P[l * 12 + q * 3 + 0]);
            ry_gate(sr, si, q, P[l * 12 + q * 3 + 1]);
            rz_gate(sr, si, q, P[l * 12 + q * 3 + 2]);
        }
        cnot_gate(sr, si, 0, 1);
        cnot_gate(sr, si, 1, 2);
        cnot_gate(sr, si, 2, 3);
        cnot_gate(sr, si, 3, 0);
    }
}

__global__ __launch_bounds__(512) void qkm_fused(
    const float* __restrict__ a, const float* __restrict__ b,
    const float* __restrict__ params, float* __restrict__ out) {

    __shared__ __align__(16) char LB[78336];
    float* Wtr  = (float*)LB;          // [y][p][17]: y*136 + p*17 + l  (34816 B)
    float* Wti  = Wtr + 8704;          // 34816 B
    float* Ptr_ = Wti + 8704;          // [i][17]: i*17 + l             (4352 B)
    float* Pti_ = Ptr_ + 1088;         // 4352 B

    const int tid = threadIdx.x;
    const int blk = blockIdx.x;
    const int xcd = blk & 7, slot = blk >> 3;    // XCD-aware swizzle (bijective, 256 blocks)
    const int bi = xcd * 2 + (slot >> 4);
    const int bj = slot & 15;
    const int row0 = bi * 64, col0 = bj * 64;

    float P[24];
    #pragma unroll
    for (int j = 0; j < 24; ++j) P[j] = params[j];

    const int y  = tid >> 3;   // M-column (and Q-row) owned by this thread, 0..63
    const int k2 = tid & 7;    // row-pair index: rows k0=2*k2, k0+1

    // ---- Phase A1: M sims, exactly one per thread (512 = 64 y x 8 p) ----
    {
        float sr[16], si[16];
        #pragma unroll
        for (int k = 0; k < 16; ++k) { sr[k] = (k == 8 + k2) ? 1.f : 0.f; si[k] = 0.f; }
        float vec[4];
        #pragma unroll
        for (int q = 0; q < 4; ++q) vec[q] = b[(col0 + y) * 4 + q];
        ansatz(sr, si, vec, P);
        float* wr = Wtr + y * 136 + k2 * 17;
        float* wi = Wti + y * 136 + k2 * 17;
        #pragma unroll
        for (int l = 0; l < 16; ++l) { wr[l] = sr[l]; wi[l] = si[l]; }
    }
    // ---- Phase A2: Q sims on wave 0 (the 9th sim pass; ceil(576/64/8)) ----
    if (tid < 64) {
        float sr[16], si[16];
        #pragma unroll
        for (int k = 0; k < 16; ++k) { sr[k] = (k == 0) ? 1.f : 0.f; si[k] = 0.f; }
        float vec[4];
        #pragma unroll
        for (int q = 0; q < 4; ++q) vec[q] = a[(row0 + tid) * 4 + q];
        ansatz(sr, si, vec, P);
        float* qr = Ptr_ + tid * 17;
        float* qi = Pti_ + tid * 17;
        #pragma unroll
        for (int l = 0; l < 16; ++l) { qr[l] = sr[l]; qi[l] = si[l]; }
    }
    __syncthreads();

    // ---- Phase B: assemble S_M rows k0,k1 of column y (l-reads shared) ----
    const int k0 = k2 * 2, k1 = k0 + 1;
    float re0[16], im0[16], re1[16], im1[16];
    #pragma unroll
    for (int l = 0; l < 16; ++l) { re0[l] = 0.f; im0[l] = 0.f; re1[l] = 0.f; im1[l] = 0.f; }
    const float* wyr = Wtr + y * 136;
    const float* wyi = Wti + y * 136;
    #pragma unroll
    for (int p2 = 0; p2 < 8; ++p2) {
        const float* br  = wyr + p2 * 17;
        const float* bi_ = wyi + p2 * 17;
        float ar0 = br[k0], ai0 = bi_[k0];   // runtime-k LDS reads: fine (17-pad)
        float ar1 = br[k1], ai1 = bi_[k1];
        #pragma unroll
        for (int l = 0; l < 16; ++l) {
            float xr = br[l], xi = bi_[l];
            re0[l] += ar0 * xr + ai0 * xi;   // Re P_{k0,l}
            im0[l] += xi * ar0 - xr * ai0;   // Im P_{l,k0}
            re1[l] += ar1 * xr + ai1 * xi;
            im1[l] += xi * ar1 - xr * ai1;
        }
    }
    float rowm0[16], rowm1[16];
    #pragma unroll
    for (int l = 0; l < 16; ++l) {
        float off0 = (l < k0) ? im0[l] : re0[l];
        rowm0[l] = (l == k0) ? (1.f - 2.f * re0[l]) : (-2.f * RT2 * off0);
        float off1 = (l < k1) ? im1[l] : re1[l];
        rowm1[l] = (l == k1) ? (1.f - 2.f * re1[l]) : (-2.f * RT2 * off1);
    }
    uint4 m00 = pack8(rowm0), m01 = pack8(rowm0 + 8);
    uint4 m10 = pack8(rowm1), m11 = pack8(rowm1 + 8);

    // ---- S_Q rows k0,k1 of row i = y (from Phi in LDS, balanced over block) ----
    const float* pr = Ptr_ + y * 17;
    const float* pi = Pti_ + y * 17;
    float rk0 = pr[k0], ik0 = pi[k0], rk1 = pr[k1], ik1 = pi[k1];
    float rowq0[16], rowq1[16];
    #pragma unroll
    for (int l = 0; l < 16; ++l) {
        float xr = pr[l], xi = pi[l];
        rowq0[l] = (l < k0)  ? RT2 * (xi * rk0 - xr * ik0)
                 : (l == k0) ? (rk0 * rk0 + ik0 * ik0)
                 :             RT2 * (rk0 * xr + ik0 * xi);
        rowq1[l] = (l < k1)  ? RT2 * (xi * rk1 - xr * ik1)
                 : (l == k1) ? (rk1 * rk1 + ik1 * ik1)
                 :             RT2 * (rk1 * xr + ik1 * xi);
    }
    uint4 q00 = pack8(rowq0), q01 = pack8(rowq0 + 8);
    uint4 q10 = pack8(rowq1), q11 = pack8(rowq1 + 8);

    __syncthreads();   // all W/Phi reads done -> safe to alias LDS with Qs/Ms

    char* Qsb = LB;                 // 64 x 512B, swizzled
    char* Msb = LB + 32768;
    {
        const int sy = (y & 15) << 4;
        *(uint4*)(Msb + y * 512 + ((k0 * 32)      ^ sy)) = m00;
        *(uint4*)(Msb + y * 512 + ((k0 * 32 + 16) ^ sy)) = m01;
        *(uint4*)(Msb + y * 512 + ((k1 * 32)      ^ sy)) = m10;
        *(uint4*)(Msb + y * 512 + ((k1 * 32 + 16) ^ sy)) = m11;
        *(uint4*)(Qsb + y * 512 + ((k0 * 32)      ^ sy)) = q00;
        *(uint4*)(Qsb + y * 512 + ((k0 * 32 + 16) ^ sy)) = q01;
        *(uint4*)(Qsb + y * 512 + ((k1 * 32)      ^ sy)) = q10;
        *(uint4*)(Qsb + y * 512 + ((k1 * 32 + 16) ^ sy)) = q11;
    }
    __syncthreads();

    // ---- Phase C: 64x64 GEMM from LDS, K=256. 8 waves: 2x4 grid of 32x16 ----
    const int wave = tid >> 6, lane = tid & 63;
    const int wi = wave >> 2, wj = wave & 3;
    const int m16 = lane & 15, quad = lane >> 4;
    const int rA0 = wi * 32 + m16;
    const int rA1 = rA0 + 16;
    const int rB  = wj * 16 + m16;
    const int sA  = m16 << 4;          // (row&15)<<4 for all three rows
    const char* qp0 = Qsb + rA0 * 512;
    const char* qp1 = Qsb + rA1 * 512;
    const char* mp  = Msb + rB  * 512;
    f32x4 a0 = {0.f, 0.f, 0.f, 0.f}, a1 = {0.f, 0.f, 0.f, 0.f};
    #pragma unroll
    for (int kk = 0; kk < 8; ++kk) {
        int cb = (kk * 64 + quad * 16) ^ sA;
        bf16x8 qa = *(const bf16x8*)(qp0 + cb);
        bf16x8 qb = *(const bf16x8*)(qp1 + cb);
        bf16x8 ma = *(const bf16x8*)(mp  + cb);
        a0 = __builtin_amdgcn_mfma_f32_16x16x32_bf16(qa, ma, a0, 0, 0, 0);
        a1 = __builtin_amdgcn_mfma_f32_16x16x32_bf16(qb, ma, a1, 0, 0, 0);
    }
    // C/D layout: col = lane&15, row = quad*4 + r  [HW-verified]
    #pragma unroll
    for (int r = 0; r < 4; ++r) {
        int orow = row0 + wi * 32 + quad * 4 + r;
        int ocol = col0 + wj * 16 + m16;
        out[orow * NB + ocol]        = fabsf(a0[r]);
        out[(orow + 16) * NB + ocol] = fabsf(a1[r]);
    }
}

extern "C" void kernel_launch(void* const* d_in, const int* in_sizes, int n_in,
                              void* d_out, int out_size, void* d_ws, size_t ws_size,
                              hipStream_t stream) {
    const float* a = (const float*)d_in[0];       // 1024 x 4
    const float* b = (const float*)d_in[1];       // 1024 x 4
    const float* params = (const float*)d_in[2];  // 2 x 4 x 3
    float* out = (float*)d_out;                   // 1024 x 1024

    (void)d_ws; (void)ws_size;                    // workspace-free
    qkm_fused<<<256, 512, 0, stream>>>(a, b, params, out);
}

// Round 2
// 80.861 us; speedup vs baseline: 1.6017x; 1.6017x over previous
//
#include <hip/hip_runtime.h>

// QuantumKernelMethod, fully fused: out[i][j] = |tr(Q_i M_j)|
// Q_i = phi phi^T (phi = V(a_i)|0>), M_j = I - 2P, P = sum_{p:wire0=1} w_p w_p^dag.
// Hermitian pack (K=256): S[k][l] = diag | sqrt2*Re (k<l) | sqrt2*Im mirror (k>l);
// dot(S_Q, S_M) = tr(QM) exactly.
//
// Single kernel, zero workspace: each 64x64 output tile block recomputes its
// 64 Q-rows + 64 M-cols in LDS, then runs the K=256 bf16 MFMA GEMM from LDS.
// 256 blocks (1/CU), 512 threads, __launch_bounds__(512,2) => VGPR cap 256,
// NO spills (round-1 failure mode: 128-VGPR cap + cross-barrier live packs
// => 260 MB of scratch traffic).
//
// LDS 143872 B, NO aliasing (so packed rows store immediately, no live-range
// across barriers):
//   Wtr/Wti [y][p][17] f32  (17-pad: sim-writes, l-reads, runtime-k reads all
//                            <=2-way bank conflicts = free)        2x34816 B
//   Phr/Phi_ [i][17] f32                                           2x 4352 B
//   Qsb/Msb bf16 64x512B, 16B-unit XOR swizzle:
//     byte = row*512 + (col ^ ((row&15)<<4)) -> conflict-free ds_read_b128
//                                                                  2x32768 B

#define NA 1024
#define NB 1024
#define RT2 1.41421356237f

typedef __attribute__((ext_vector_type(8))) short bf16x8;
typedef __attribute__((ext_vector_type(4))) float f32x4;

__device__ __forceinline__ unsigned short f2bf(float x) {
    union { float f; unsigned u; } v; v.f = x;
    unsigned r = v.u + 0x7fffu + ((v.u >> 16) & 1u);  // RNE
    return (unsigned short)(r >> 16);
}

__device__ __forceinline__ uint4 pack8(const float* f) {
    uint4 u;
    u.x = (unsigned)f2bf(f[0]) | ((unsigned)f2bf(f[1]) << 16);
    u.y = (unsigned)f2bf(f[2]) | ((unsigned)f2bf(f[3]) << 16);
    u.z = (unsigned)f2bf(f[4]) | ((unsigned)f2bf(f[5]) << 16);
    u.w = (unsigned)f2bf(f[6]) | ((unsigned)f2bf(f[7]) << 16);
    return u;
}

// State: 16 complex amps, flat index = b0*8 + b1*4 + b2*2 + b3 (wire w -> bit 3-w)
__device__ __forceinline__ void ry_gate(float* sr, float* si, int w, float t) {
    float s, c; __sincosf(0.5f * t, &s, &c);
    int st = 8 >> w;
    #pragma unroll
    for (int b = 0; b < 16; ++b) {
        if (b & st) continue;
        int j = b | st;
        float r0 = sr[b], i0 = si[b], r1 = sr[j], i1 = si[j];
        sr[b] = c * r0 - s * r1;  si[b] = c * i0 - s * i1;
        sr[j] = s * r0 + c * r1;  si[j] = s * i0 + c * i1;
    }
}

__device__ __forceinline__ void rx_gate(float* sr, float* si, int w, float t) {
    float s, c; __sincosf(0.5f * t, &s, &c);
    int st = 8 >> w;
    #pragma unroll
    for (int b = 0; b < 16; ++b) {
        if (b & st) continue;
        int j = b | st;
        float r0 = sr[b], i0 = si[b], r1 = sr[j], i1 = si[j];
        sr[b] = c * r0 + s * i1;  si[b] = c * i0 - s * r1;
        sr[j] = c * r1 + s * i0;  si[j] = c * i1 - s * r0;
    }
}

__device__ __forceinline__ void rz_gate(float* sr, float* si, int w, float t) {
    float s, c; __sincosf(0.5f * t, &s, &c);
    int st = 8 >> w;
    #pragma unroll
    for (int b = 0; b < 16; ++b) {
        if (b & st) continue;
        int j = b | st;
        float r0 = sr[b], i0 = si[b], r1 = sr[j], i1 = si[j];
        sr[b] = c * r0 + s * i0;  si[b] = c * i0 - s * r0;
        sr[j] = c * r1 - s * i1;  si[j] = c * i1 + s * r1;
    }
}

__device__ __forceinline__ void cnot_gate(float* sr, float* si, int cw, int tw) {
    int cs = 8 >> cw, ts = 8 >> tw;
    #pragma unroll
    for (int b = 0; b < 16; ++b) {
        if ((b & cs) && !(b & ts)) {
            int j = b | ts;
            float tr = sr[b]; sr[b] = sr[j]; sr[j] = tr;
            float ti = si[b]; si[b] = si[j]; si[j] = ti;
        }
    }
}

__device__ __forceinline__ void ansatz(float* sr, float* si, const float* vec, const float* P) {
    #pragma unroll
    for (int q = 0; q < 4; ++q) ry_gate(sr, si, q, vec[q]);
    #pragma unroll
    for (int l = 0; l < 2; ++l) {
        #pragma unroll
        for (int q = 0; q < 4; ++q) {
            rx_gate(sr, si, q, P[l * 12 + q * 3 + 0]);
            ry_gate(sr, si, q, P[l * 12 + q * 3 + 1]);
            rz_gate(sr, si, q, P[l * 12 + q * 3 + 2]);
        }
        cnot_gate(sr, si, 0, 1);
        cnot_gate(sr, si, 1, 2);
        cnot_gate(sr, si, 2, 3);
        cnot_gate(sr, si, 3, 0);
    }
}

__global__ __launch_bounds__(512, 2) void qkm_fused(
    const float* __restrict__ a, const float* __restrict__ b,
    const float* __restrict__ params, float* __restrict__ out) {

    __shared__ float Wtr[64 * 136];             // [y][p][17]
    __shared__ float Wti[64 * 136];
    __shared__ float Phr[64 * 17];              // [i][17]
    __shared__ float Phi_[64 * 17];
    __shared__ __align__(16) char Qsb[32768];   // 64 x 512B, swizzled
    __shared__ __align__(16) char Msb[32768];

    const int tid = threadIdx.x;
    const int blk = blockIdx.x;
    const int xcd = blk & 7, slot = blk >> 3;   // XCD-aware swizzle (bijective, 256 blocks)
    const int bi = xcd * 2 + (slot >> 4);
    const int bj = slot & 15;
    const int row0 = bi * 64, col0 = bj * 64;

    float P[24];
    #pragma unroll
    for (int j = 0; j < 24; ++j) P[j] = params[j];

    const int y  = tid >> 3;   // M-column / Q-row owned by this thread, 0..63
    const int k2 = tid & 7;    // row-pair index: rows k0=2*k2, k0+1
    const int k0 = k2 * 2;
    const int sy = (y & 15) << 4;

    // ---- Phase A1: M sims, exactly one per thread (512 = 64 y x 8 p) ----
    {
        float sr[16], si[16];
        #pragma unroll
        for (int k = 0; k < 16; ++k) { sr[k] = (k == 8 + k2) ? 1.f : 0.f; si[k] = 0.f; }
        float vec[4];
        #pragma unroll
        for (int q = 0; q < 4; ++q) vec[q] = b[(col0 + y) * 4 + q];
        ansatz(sr, si, vec, P);
        float* wr = Wtr + y * 136 + k2 * 17;
        float* wi = Wti + y * 136 + k2 * 17;
        #pragma unroll
        for (int l = 0; l < 16; ++l) { wr[l] = sr[l]; wi[l] = si[l]; }
    }
    __syncthreads();   // W complete

    // ---- Phase A2: Q sims on wave 0, overlapped with waves 1-7's S_M work ----
    if (tid < 64) {
        float sr[16], si[16];
        #pragma unroll
        for (int k = 0; k < 16; ++k) { sr[k] = (k == 0) ? 1.f : 0.f; si[k] = 0.f; }
        float vec[4];
        #pragma unroll
        for (int q = 0; q < 4; ++q) vec[q] = a[(row0 + tid) * 4 + q];
        ansatz(sr, si, vec, P);
        float* qr = Phr + tid * 17;
        float* qi = Phi_ + tid * 17;
        #pragma unroll
        for (int l = 0; l < 16; ++l) { qr[l] = sr[l]; qi[l] = si[l]; }
    }

    // ---- Phase B-M: S_M rows k0,k0+1 of column y; one row at a time, store
    //      packed row to LDS immediately (nothing live across barriers) ----
    {
        const float* wyr = Wtr + y * 136;
        const float* wyi = Wti + y * 136;
        #pragma unroll
        for (int rr = 0; rr < 2; ++rr) {
            const int k = k0 + rr;
            float re[16], im[16];
            #pragma unroll
            for (int l = 0; l < 16; ++l) { re[l] = 0.f; im[l] = 0.f; }
            #pragma unroll
            for (int p2 = 0; p2 < 8; ++p2) {
                const float* br  = wyr + p2 * 17;
                const float* bi_ = wyi + p2 * 17;
                float ar = br[k], ai = bi_[k];     // runtime-k read: 2-way, free
                #pragma unroll
                for (int l = 0; l < 16; ++l) {
                    float xr = br[l], xi = bi_[l]; // broadcast within y-group
                    re[l] += ar * xr + ai * xi;    // Re P_{k,l}
                    im[l] += xi * ar - xr * ai;    // Im P_{l,k}
                }
            }
            float row[16];
            #pragma unroll
            for (int l = 0; l < 16; ++l) {
                float off = (l < k) ? im[l] : re[l];
                row[l] = (l == k) ? (1.f - 2.f * re[l]) : (-2.f * RT2 * off);
            }
            *(uint4*)(Msb + y * 512 + ((k * 32)      ^ sy)) = pack8(row);
            *(uint4*)(Msb + y * 512 + ((k * 32 + 16) ^ sy)) = pack8(row + 8);
        }
    }
    __syncthreads();   // Phi ready (wave 0), Ms done

    // ---- Phase B-Q: S_Q rows k0,k0+1 of row i=y (cheap: rank-1) ----
    {
        const float* pr = Phr + y * 17;
        const float* pi = Phi_ + y * 17;
        #pragma unroll
        for (int rr = 0; rr < 2; ++rr) {
            const int k = k0 + rr;
            float rk = pr[k], ik = pi[k];
            float row[16];
            #pragma unroll
            for (int l = 0; l < 16; ++l) {
                float xr = pr[l], xi = pi[l];
                row[l] = (l < k)  ? RT2 * (xi * rk - xr * ik)
                       : (l == k) ? (rk * rk + ik * ik)
                       :            RT2 * (rk * xr + ik * xi);
            }
            *(uint4*)(Qsb + y * 512 + ((k * 32)      ^ sy)) = pack8(row);
            *(uint4*)(Qsb + y * 512 + ((k * 32 + 16) ^ sy)) = pack8(row + 8);
        }
    }
    __syncthreads();   // Qs done

    // ---- Phase C: 64x64 GEMM from LDS, K=256. 8 waves: 2x4 grid of 32x16 ----
    const int wave = tid >> 6, lane = tid & 63;
    const int wi = wave >> 2, wj = wave & 3;
    const int m16 = lane & 15, quad = lane >> 4;
    const int rA0 = wi * 32 + m16;
    const int rA1 = rA0 + 16;
    const int rB  = wj * 16 + m16;
    const int sA  = m16 << 4;          // (row&15)<<4 for all three rows
    const char* qp0 = Qsb + rA0 * 512;
    const char* qp1 = Qsb + rA1 * 512;
    const char* mp  = Msb + rB  * 512;
    f32x4 a0 = {0.f, 0.f, 0.f, 0.f}, a1 = {0.f, 0.f, 0.f, 0.f};
    #pragma unroll
    for (int kk = 0; kk < 8; ++kk) {
        int cb = (kk * 64 + quad * 16) ^ sA;
        bf16x8 qa = *(const bf16x8*)(qp0 + cb);
        bf16x8 qb = *(const bf16x8*)(qp1 + cb);
        bf16x8 ma = *(const bf16x8*)(mp  + cb);
        a0 = __builtin_amdgcn_mfma_f32_16x16x32_bf16(qa, ma, a0, 0, 0, 0);
        a1 = __builtin_amdgcn_mfma_f32_16x16x32_bf16(qb, ma, a1, 0, 0, 0);
    }
    // C/D layout: col = lane&15, row = quad*4 + r  [HW-verified]
    #pragma unroll
    for (int r = 0; r < 4; ++r) {
        int orow = row0 + wi * 32 + quad * 4 + r;
        int ocol = col0 + wj * 16 + m16;
        out[orow * NB + ocol]        = fabsf(a0[r]);
        out[(orow + 16) * NB + ocol] = fabsf(a1[r]);
    }
}

extern "C" void kernel_launch(void* const* d_in, const int* in_sizes, int n_in,
                              void* d_out, int out_size, void* d_ws, size_t ws_size,
                              hipStream_t stream) {
    const float* a = (const float*)d_in[0];       // 1024 x 4
    const float* b = (const float*)d_in[1];       // 1024 x 4
    const float* params = (const float*)d_in[2];  // 2 x 4 x 3
    float* out = (float*)d_out;                   // 1024 x 1024

    (void)d_ws; (void)ws_size;                    // workspace-free
    qkm_fused<<<256, 512, 0, stream>>>(a, b, params, out);
}

// Round 3
// 75.688 us; speedup vs baseline: 1.7112x; 1.0683x over previous
//
#include <hip/hip_runtime.h>

// QuantumKernelMethod: out[i][j] = |tr(Q_i M_j)|
// Q_i = phi phi^T (phi = V(a_i)|0>), M_j = V(b_j) Z0 V(b_j)^dag = I - 2P,
// P = sum_{p: wire0bit=1} w_p w_p^dag (8 basis sims per y).
// Hermitian pack (K=256): S[k][l] = diag | sqrt2*Re (k<l) | sqrt2*Im mirror (k>l);
// dot(S_Q, S_M) = tr(QM) exactly. out = |Q(1024x256) * M(1024x256)^T|.
//
// Two kernels (round-0 structure, proven): fusion costs 16x redundant sims.
// Phase1 rebuilt wide: 34 blocks x 512 thr (was 144 x 64 = 1 wave/block,
// latency-bound with 544 scalar ds_read_b32/thread).
//  - blocks 0..31: M. 32 y/block; 256 sims (1/thread, waves 0-3); W in LDS
//    [y][p][17] split f32 (l-reads vectorize to ds_read_b128 4-addr
//    broadcasts, conflict-free; runtime-k scalar reads <=2-way = free).
//    Assembly: 512 rows = 1 row/thread, ~80 LDS insts (vs 544 scalar).
//  - blocks 32..33: Q. 1 sim/thread, rank-1 rows from registers.
// Phase2: unchanged (L2-resident S, 64x64 MFMA tiles, ~4-6 us, not the
// bottleneck). Harness floor: 256 MiB ws poison ~41 us + ~10 us overhead.

#define NA 1024
#define NB 1024
#define KD 256
#define RT2 1.41421356237f

typedef __attribute__((ext_vector_type(8))) short bf16x8;
typedef __attribute__((ext_vector_type(4))) float f32x4;

__device__ __forceinline__ unsigned short f2bf(float x) {
    union { float f; unsigned u; } v; v.f = x;
    unsigned r = v.u + 0x7fffu + ((v.u >> 16) & 1u);  // RNE
    return (unsigned short)(r >> 16);
}

__device__ __forceinline__ uint4 pack8(const float* f) {
    uint4 u;
    u.x = (unsigned)f2bf(f[0]) | ((unsigned)f2bf(f[1]) << 16);
    u.y = (unsigned)f2bf(f[2]) | ((unsigned)f2bf(f[3]) << 16);
    u.z = (unsigned)f2bf(f[4]) | ((unsigned)f2bf(f[5]) << 16);
    u.w = (unsigned)f2bf(f[6]) | ((unsigned)f2bf(f[7]) << 16);
    return u;
}

// State: 16 complex amps, flat index = b0*8 + b1*4 + b2*2 + b3 (wire w -> bit 3-w)
__device__ __forceinline__ void ry_gate(float* sr, float* si, int w, float t) {
    float s, c; __sincosf(0.5f * t, &s, &c);
    int st = 8 >> w;
    #pragma unroll
    for (int b = 0; b < 16; ++b) {
        if (b & st) continue;
        int j = b | st;
        float r0 = sr[b], i0 = si[b], r1 = sr[j], i1 = si[j];
        sr[b] = c * r0 - s * r1;  si[b] = c * i0 - s * i1;
        sr[j] = s * r0 + c * r1;  si[j] = s * i0 + c * i1;
    }
}

__device__ __forceinline__ void rx_gate(float* sr, float* si, int w, float t) {
    float s, c; __sincosf(0.5f * t, &s, &c);
    int st = 8 >> w;
    #pragma unroll
    for (int b = 0; b < 16; ++b) {
        if (b & st) continue;
        int j = b | st;
        float r0 = sr[b], i0 = si[b], r1 = sr[j], i1 = si[j];
        sr[b] = c * r0 + s * i1;  si[b] = c * i0 - s * r1;
        sr[j] = c * r1 + s * i0;  si[j] = c * i1 - s * r0;
    }
}

__device__ __forceinline__ void rz_gate(float* sr, float* si, int w, float t) {
    float s, c; __sincosf(0.5f * t, &s, &c);
    int st = 8 >> w;
    #pragma unroll
    for (int b = 0; b < 16; ++b) {
        if (b & st) continue;
        int j = b | st;
        float r0 = sr[b], i0 = si[b], r1 = sr[j], i1 = si[j];
        sr[b] = c * r0 + s * i0;  si[b] = c * i0 - s * r0;
        sr[j] = c * r1 - s * i1;  si[j] = c * i1 + s * r1;
    }
}

__device__ __forceinline__ void cnot_gate(float* sr, float* si, int cw, int tw) {
    int cs = 8 >> cw, ts = 8 >> tw;
    #pragma unroll
    for (int b = 0; b < 16; ++b) {
        if ((b & cs) && !(b & ts)) {
            int j = b | ts;
            float tr = sr[b]; sr[b] = sr[j]; sr[j] = tr;
            float ti = si[b]; si[b] = si[j]; si[j] = ti;
        }
    }
}

__device__ __forceinline__ void ansatz(float* sr, float* si, const float* vec, const float* P) {
    #pragma unroll
    for (int q = 0; q < 4; ++q) ry_gate(sr, si, q, vec[q]);
    #pragma unroll
    for (int l = 0; l < 2; ++l) {
        #pragma unroll
        for (int q = 0; q < 4; ++q) {
            rx_gate(sr, si, q, P[l * 12 + q * 3 + 0]);
            ry_gate(sr, si, q, P[l * 12 + q * 3 + 1]);
            rz_gate(sr, si, q, P[l * 12 + q * 3 + 2]);
        }
        cnot_gate(sr, si, 0, 1);
        cnot_gate(sr, si, 1, 2);
        cnot_gate(sr, si, 2, 3);
        cnot_gate(sr, si, 3, 0);
    }
}

__global__ __launch_bounds__(512, 2) void qkm_phase1(
    const float* __restrict__ a, const float* __restrict__ b,
    const float* __restrict__ params,
    uint4* __restrict__ Qv, uint4* __restrict__ Mv) {

    float P[24];
    #pragma unroll
    for (int j = 0; j < 24; ++j) P[j] = params[j];
    const int tid = threadIdx.x;
    const int blk = blockIdx.x;

    if (blk < 32) {
        // ---- M-part: 32 y's, W[y][p][17] split f32 in LDS ----
        __shared__ float Wtr[32 * 136];
        __shared__ float Wti[32 * 136];
        const int col0 = blk << 5;

        if (tid < 256) {
            const int y = tid >> 3, p2 = tid & 7;
            float sr[16], si[16];
            #pragma unroll
            for (int k = 0; k < 16; ++k) { sr[k] = (k == 8 + p2) ? 1.f : 0.f; si[k] = 0.f; }
            float vec[4];
            #pragma unroll
            for (int q = 0; q < 4; ++q) vec[q] = b[(col0 + y) * 4 + q];
            ansatz(sr, si, vec, P);
            float* wr = Wtr + y * 136 + p2 * 17;
            float* wi = Wti + y * 136 + p2 * 17;
            #pragma unroll
            for (int l = 0; l < 16; ++l) { wr[l] = sr[l]; wi[l] = si[l]; }
        }
        __syncthreads();

        // Assembly: 1 row per thread. y = tid>>4, k = tid&15.
        const int y = tid >> 4, k = tid & 15;
        const float* wyr = Wtr + y * 136;
        const float* wyi = Wti + y * 136;
        float re[16], im[16];
        #pragma unroll
        for (int l = 0; l < 16; ++l) { re[l] = 0.f; im[l] = 0.f; }
        #pragma unroll
        for (int p2 = 0; p2 < 8; ++p2) {
            const float* br  = wyr + p2 * 17;
            const float* bi_ = wyi + p2 * 17;
            float ar = br[k], ai = bi_[k];     // runtime-k: <=2-way, free
            #pragma unroll
            for (int l = 0; l < 16; ++l) {
                float xr = br[l], xi = bi_[l]; // b128 4-addr broadcast, free
                re[l] += ar * xr + ai * xi;    // Re P_{k,l}
                im[l] += xi * ar - xr * ai;    // Im P_{l,k}
            }
        }
        float row[16];
        #pragma unroll
        for (int l = 0; l < 16; ++l) {
            float off = (l < k) ? im[l] : re[l];
            row[l] = (l == k) ? (1.f - 2.f * re[l]) : (-2.f * RT2 * off);
        }
        uint4* d = Mv + (size_t)(col0 + y) * 32 + k * 2;
        d[0] = pack8(row); d[1] = pack8(row + 8);
    } else {
        // ---- Q-part: blocks 32,33; 1 statevector sim per thread ----
        const int i = ((blk - 32) << 9) + tid;
        float sr[16], si[16];
        #pragma unroll
        for (int k = 0; k < 16; ++k) { sr[k] = (k == 0) ? 1.f : 0.f; si[k] = 0.f; }
        float vec[4];
        #pragma unroll
        for (int q = 0; q < 4; ++q) vec[q] = a[i * 4 + q];
        ansatz(sr, si, vec, P);
        // Q = phi phi^dag: Re Q_kl = rk*rl + ik*il; Im Q_lk = il*rk - rl*ik
        #pragma unroll
        for (int k = 0; k < 16; ++k) {
            float rk = sr[k], ik = si[k];
            float row[16];
            #pragma unroll
            for (int l = 0; l < 16; ++l) {
                if (l < k)       row[l] = RT2 * (si[l] * rk - sr[l] * ik);
                else if (l == k) row[l] = rk * rk + ik * ik;
                else             row[l] = RT2 * (rk * sr[l] + ik * si[l]);
            }
            uint4* d = Qv + (size_t)i * 32 + k * 2;
            d[0] = pack8(row); d[1] = pack8(row + 8);
        }
    }
}

// Phase 2: out = |Q * M^T|, bf16 MFMA, K=256. 64x64 tile/block, 4 waves 2x2,
// each wave 32x32 = 2x2 fragments. XCD swizzle: xcd=blk&7 owns a Q-row band.
__global__ __launch_bounds__(256) void qkm_phase2(
    const unsigned short* __restrict__ Q, const unsigned short* __restrict__ M,
    float* __restrict__ out) {
    int wave = threadIdx.x >> 6;
    int lane = threadIdx.x & 63;
    int blk = blockIdx.x;
    int xcd = blk & 7;
    int slot = blk >> 3;                 // [0,32)
    int bi = xcd * 2 + (slot >> 4);      // [0,16)
    int bj = slot & 15;                  // [0,16)
    int wi = wave >> 1, wj = wave & 1;
    int row0 = bi * 64 + wi * 32;
    int col0 = bj * 64 + wj * 32;
    int m16 = lane & 15;
    int quad = lane >> 4;

    const unsigned short* q0 = Q + (size_t)(row0 + m16) * KD + quad * 8;
    const unsigned short* q1 = q0 + 16 * KD;
    const unsigned short* m0 = M + (size_t)(col0 + m16) * KD + quad * 8;
    const unsigned short* m1 = m0 + 16 * KD;

    f32x4 a00 = {0.f,0.f,0.f,0.f}, a01 = {0.f,0.f,0.f,0.f};
    f32x4 a10 = {0.f,0.f,0.f,0.f}, a11 = {0.f,0.f,0.f,0.f};
    #pragma unroll
    for (int kk = 0; kk < 8; ++kk) {
        bf16x8 qa = *(const bf16x8*)(q0 + kk * 32);
        bf16x8 qb = *(const bf16x8*)(q1 + kk * 32);
        bf16x8 ma = *(const bf16x8*)(m0 + kk * 32);
        bf16x8 mb = *(const bf16x8*)(m1 + kk * 32);
        a00 = __builtin_amdgcn_mfma_f32_16x16x32_bf16(qa, ma, a00, 0, 0, 0);
        a01 = __builtin_amdgcn_mfma_f32_16x16x32_bf16(qa, mb, a01, 0, 0, 0);
        a10 = __builtin_amdgcn_mfma_f32_16x16x32_bf16(qb, ma, a10, 0, 0, 0);
        a11 = __builtin_amdgcn_mfma_f32_16x16x32_bf16(qb, mb, a11, 0, 0, 0);
    }
    // C/D layout: col = lane&15, row = quad*4 + r  [HW-verified]
    #pragma unroll
    for (int r = 0; r < 4; ++r) {
        int r0o = row0 + quad * 4 + r;
        int r1o = r0o + 16;
        out[r0o * NB + col0 + m16]      = fabsf(a00[r]);
        out[r0o * NB + col0 + 16 + m16] = fabsf(a01[r]);
        out[r1o * NB + col0 + m16]      = fabsf(a10[r]);
        out[r1o * NB + col0 + 16 + m16] = fabsf(a11[r]);
    }
}

extern "C" void kernel_launch(void* const* d_in, const int* in_sizes, int n_in,
                              void* d_out, int out_size, void* d_ws, size_t ws_size,
                              hipStream_t stream) {
    const float* a = (const float*)d_in[0];       // 1024 x 4
    const float* b = (const float*)d_in[1];       // 1024 x 4
    const float* params = (const float*)d_in[2];  // 2 x 4 x 3
    float* out = (float*)d_out;                   // 1024 x 1024

    unsigned short* Q = (unsigned short*)d_ws;            // NA x 256 bf16
    unsigned short* M = Q + (size_t)NA * KD;              // NB x 256 bf16

    qkm_phase1<<<34, 512, 0, stream>>>(a, b, params, (uint4*)Q, (uint4*)M);
    qkm_phase2<<<256, 256, 0, stream>>>(Q, M, out);
}